// Round 3
// baseline (50.741 us; speedup 1.0000x reference)
//
#include <hip/hip_runtime.h>

#define N_IN    256
#define N_EVAL  1088
#define TOTALW  (N_IN + N_EVAL)   // 1344
#define DEG     32
#define TILE_B  8
#define NTHREADS 256

// Transposed LDS layout: float index for (col c, batch b) = (c*8 + b),
// XOR-swizzled in bits [4:2] so 16B granules hash over all 8 bank-groups.
__device__ __forceinline__ int swz_base(int c) {
    return (c << 3) ^ (((c >> 2) & 7) << 2);
}
// bank-group (granule index mod 8) of the read at swz_base(c)
__device__ __forceinline__ int ggroup(int c) {
    return ((c << 1) ^ ((c >> 2) & 7)) & 7;
}

// Per-neuron schedule: stable-sort the 32 (idx,w) pairs by bank-group, then
// rotate by (n & 31) so that lanes of a wave hit disjoint strata each step.
__global__ __launch_bounds__(256) void neat_sort(
    const int* __restrict__ src, const float* __restrict__ w,
    int* __restrict__ idx2, float* __restrict__ w2)
{
    int t    = blockIdx.x * blockDim.x + threadIdx.x;
    int wid  = t >> 6;              // wave id, 2 neurons per wave
    int lane = threadIdx.x & 63;
    int half = lane >> 5;
    int k    = lane & 31;
    int n    = wid * 2 + half;      // N_EVAL = 1088 = 2*544, exact fit
    int   c  = src[n * DEG + k];
    float wv = w[n * DEG + k];
    int   g  = ggroup(c);
    unsigned long long mfull[8];
    #pragma unroll
    for (int v = 0; v < 8; ++v) mfull[v] = __ballot(g == v);
    unsigned int mh[8];
    #pragma unroll
    for (int v = 0; v < 8; ++v)
        mh[v] = (unsigned int)(half ? (mfull[v] >> 32) : (mfull[v] & 0xffffffffull));
    int rank = __popc(mh[g] & ((1u << k) - 1u));
    #pragma unroll
    for (int v = 0; v < 8; ++v) if (v < g) rank += __popc(mh[v]);
    int p = (rank - (n & 31)) & 31;   // out[j] = sorted[(j + (n&31)) & 31]
    idx2[n * DEG + p] = c;
    w2[n * DEG + p]   = wv;
}

__device__ __forceinline__ void colacc(const float* __restrict__ vals, int c, float wv,
                                       float4& accA, float4& accB) {
    int f = swz_base(c);
    const float4 a = *(const float4*)(vals + f);        // rows 0..3
    const float4 b = *(const float4*)(vals + (f ^ 4));  // rows 4..7
    accA.x = fmaf(a.x, wv, accA.x); accA.y = fmaf(a.y, wv, accA.y);
    accA.z = fmaf(a.z, wv, accA.z); accA.w = fmaf(a.w, wv, accA.w);
    accB.x = fmaf(b.x, wv, accB.x); accB.y = fmaf(b.y, wv, accB.y);
    accB.z = fmaf(b.z, wv, accB.z); accB.w = fmaf(b.w, wv, accB.w);
}

__global__ __launch_bounds__(NTHREADS) void neat_eval(
    const float* __restrict__ x, const float* __restrict__ w,
    const float* __restrict__ bias, const float* __restrict__ resp,
    const int* __restrict__ src, float* __restrict__ out)
{
    __shared__ float vals[TILE_B * TOTALW];   // 43,008 B, transposed+swizzled
    const int tid = threadIdx.x;
    const int b0  = blockIdx.x * TILE_B;

    #pragma unroll
    for (int i = 0; i < 2; ++i) {
        int idx = tid + i * NTHREADS;      // 0..511
        int cq  = idx & 63;                // column quad
        int b   = idx >> 6;                // batch row 0..7
        float4 x4 = *(const float4*)(x + (size_t)(b0 + b) * N_IN + cq * 4);
        int badj = b & 3, bx = b & 4;
        vals[((swz_base(cq * 4 + 0)) ^ bx) + badj] = x4.x;
        vals[((swz_base(cq * 4 + 1)) ^ bx) + badj] = x4.y;
        vals[((swz_base(cq * 4 + 2)) ^ bx) + badj] = x4.z;
        vals[((swz_base(cq * 4 + 3)) ^ bx) + badj] = x4.w;
    }
    __syncthreads();

    int row = 0;
    int outoff = N_IN;
    #pragma unroll
    for (int li = 0; li < 5; ++li) {
        const int sz = (li < 4) ? 256 : 64;
        for (int n = tid; n < sz; n += NTHREADS) {
            const int gr = row + n;
            const int4*   s4 = (const int4*)(src + (size_t)gr * DEG);
            const float4* w4 = (const float4*)(w   + (size_t)gr * DEG);
            float4 accA = {0.f, 0.f, 0.f, 0.f};
            float4 accB = {0.f, 0.f, 0.f, 0.f};
            #pragma unroll
            for (int k = 0; k < DEG / 4; ++k) {
                int4   i4 = s4[k];
                float4 wv = w4[k];
                colacc(vals, i4.x, wv.x, accA, accB);
                colacc(vals, i4.y, wv.y, accA, accB);
                colacc(vals, i4.z, wv.z, accA, accB);
                colacc(vals, i4.w, wv.w, accA, accB);
            }
            const float bb = bias[gr], rr = resp[gr];
            accA.x = fmaxf(fmaf(rr, accA.x, bb), 0.f);
            accA.y = fmaxf(fmaf(rr, accA.y, bb), 0.f);
            accA.z = fmaxf(fmaf(rr, accA.z, bb), 0.f);
            accA.w = fmaxf(fmaf(rr, accA.w, bb), 0.f);
            accB.x = fmaxf(fmaf(rr, accB.x, bb), 0.f);
            accB.y = fmaxf(fmaf(rr, accB.y, bb), 0.f);
            accB.z = fmaxf(fmaf(rr, accB.z, bb), 0.f);
            accB.w = fmaxf(fmaf(rr, accB.w, bb), 0.f);
            int fo = swz_base(outoff + n);
            *(float4*)(vals + fo)       = accA;
            *(float4*)(vals + (fo ^ 4)) = accB;
        }
        __syncthreads();
        row += sz;
        outoff += sz;
    }

    #pragma unroll
    for (int i = 0; i < 2; ++i) {
        int idx = tid + i * NTHREADS;      // 0..511
        int c = idx & 63;
        int b = idx >> 6;
        int oc = TOTALW - 64 + c;
        float v = vals[((swz_base(oc)) ^ (b & 4)) + (b & 3)];
        out[(size_t)(b0 + b) * 64 + c] = v;
    }
}

extern "C" void kernel_launch(void* const* d_in, const int* in_sizes, int n_in,
                              void* d_out, int out_size, void* d_ws, size_t ws_size,
                              hipStream_t stream) {
    const float* x    = (const float*)d_in[0];
    const float* w    = (const float*)d_in[1];
    const float* bias = (const float*)d_in[2];
    const float* resp = (const float*)d_in[3];
    const int*   src  = (const int*)d_in[4];
    float* out = (float*)d_out;

    const int batch = in_sizes[0] / N_IN;        // 8192
    const int grid  = batch / TILE_B;            // 1024 blocks

    const size_t idx_bytes = (size_t)N_EVAL * DEG * sizeof(int);
    const size_t need = idx_bytes + (size_t)N_EVAL * DEG * sizeof(float);

    const int*   use_src = src;
    const float* use_w   = w;
    if (ws_size >= need) {
        int*   idx2 = (int*)d_ws;
        float* w2   = (float*)((char*)d_ws + idx_bytes);
        // 1088 neurons, 2 per wave -> 544 waves -> 136 blocks of 256
        neat_sort<<<(N_EVAL / 2 * 64) / 256, 256, 0, stream>>>(src, w, idx2, w2);
        use_src = idx2;
        use_w   = w2;
    }
    neat_eval<<<grid, NTHREADS, 0, stream>>>(x, use_w, bias, resp, use_src, out);
}

// Round 4
// 30.316 us; speedup vs baseline: 1.6737x; 1.6737x over previous
//
#include <hip/hip_runtime.h>

#define N_IN    256
#define N_EVAL  1088
#define TOTALW  1344
#define DEG     32
#define TILE_B  16
#define NTHREADS 256

// Byte offset of 16B granule (column c, half h). Column c = 16 rows bf16 = 32B
// = 2 granules (h=0: rows 0-7, h=1: rows 8-15). XOR-hash bits of c into the
// bank-group bits [7:5] so random columns spread over all 8 bank groups.
// Bijective: (byte>>5) = c ^ ((c>>2)&7), triangular in low bits; bit4 = h.
__device__ __forceinline__ int gbyte(int c, int h) {
    return ((c << 5) + (h << 4)) ^ (int)((((unsigned)c >> 2) & 7u) << 5);
}

// Pack two floats to bf16 pair (RNE), lo in low 16 bits, hi in high 16 bits.
__device__ __forceinline__ unsigned int bf16rne2(float lo, float hi) {
    unsigned int ul = __float_as_uint(lo);
    unsigned int uh = __float_as_uint(hi);
    ul = (ul + 0x7fffu + ((ul >> 16) & 1u)) >> 16;
    uh = (uh + 0x7fffu + ((uh >> 16) & 1u)) & 0xffff0000u;
    return ul | uh;
}

__device__ __forceinline__ void fmadw(unsigned int d, float wv, float* acc) {
    acc[0] = fmaf(__uint_as_float(d << 16), wv, acc[0]);
    acc[1] = fmaf(__uint_as_float(d & 0xffff0000u), wv, acc[1]);
}

__device__ __forceinline__ void colacc16(const unsigned int* vals, int c, float wv,
                                         float* acc) {
    const uint4* p = (const uint4*)((const char*)vals + gbyte(c, 0));
    uint4 a = p[0];   // rows 0..7
    uint4 b = p[1];   // rows 8..15 (gbyte(c,1) == gbyte(c,0)+16)
    fmadw(a.x, wv, acc + 0);  fmadw(a.y, wv, acc + 2);
    fmadw(a.z, wv, acc + 4);  fmadw(a.w, wv, acc + 6);
    fmadw(b.x, wv, acc + 8);  fmadw(b.y, wv, acc + 10);
    fmadw(b.z, wv, acc + 12); fmadw(b.w, wv, acc + 14);
}

__global__ __launch_bounds__(NTHREADS) void neat_eval(
    const float* __restrict__ x, const float* __restrict__ w,
    const float* __restrict__ bias, const float* __restrict__ resp,
    const int* __restrict__ src, float* __restrict__ out)
{
    __shared__ unsigned int vals[TOTALW * 8];   // 43,008 B (bf16, 16 rows/col)
    const int tid = threadIdx.x;
    const int b0  = blockIdx.x * TILE_B;

    // Stage x as bf16, transposed: granule (c,h) holds rows 8h..8h+7 of col c.
    // 256 cols x 2 halves = 512 granules; global loads coalesced across lanes.
    #pragma unroll
    for (int i = 0; i < 2; ++i) {
        int g = tid + i * NTHREADS;     // 0..511
        int c = g & 255;
        int h = g >> 8;
        unsigned int pk[4];
        #pragma unroll
        for (int j = 0; j < 4; ++j) {
            float lo = x[(size_t)(b0 + h * 8 + 2 * j    ) * N_IN + c];
            float hi = x[(size_t)(b0 + h * 8 + 2 * j + 1) * N_IN + c];
            pk[j] = bf16rne2(lo, hi);
        }
        *(uint4*)((char*)vals + gbyte(c, h)) = make_uint4(pk[0], pk[1], pk[2], pk[3]);
    }
    __syncthreads();

    int row = 0, outoff = N_IN;
    #pragma unroll
    for (int li = 0; li < 5; ++li) {
        const int sz = (li < 4) ? 256 : 64;
        for (int n = tid; n < sz; n += NTHREADS) {
            const int gr = row + n;
            const int4*   s4 = (const int4*)(src + (size_t)gr * DEG);
            const float4* w4 = (const float4*)(w   + (size_t)gr * DEG);
            float acc[16];
            #pragma unroll
            for (int i = 0; i < 16; ++i) acc[i] = 0.f;
            #pragma unroll
            for (int k = 0; k < DEG / 4; ++k) {
                int4   i4 = s4[k];
                float4 wv = w4[k];
                colacc16(vals, i4.x, wv.x, acc);
                colacc16(vals, i4.y, wv.y, acc);
                colacc16(vals, i4.z, wv.z, acc);
                colacc16(vals, i4.w, wv.w, acc);
            }
            const float bb = bias[gr], rr = resp[gr];
            unsigned int pk[8];
            #pragma unroll
            for (int j = 0; j < 8; ++j) {
                float lo = fmaxf(fmaf(rr, acc[2 * j    ], bb), 0.f);
                float hi = fmaxf(fmaf(rr, acc[2 * j + 1], bb), 0.f);
                pk[j] = bf16rne2(lo, hi);
            }
            int ob = gbyte(outoff + n, 0);
            *(uint4*)((char*)vals + ob)      = make_uint4(pk[0], pk[1], pk[2], pk[3]);
            *(uint4*)((char*)vals + ob + 16) = make_uint4(pk[4], pk[5], pk[6], pk[7]);
        }
        __syncthreads();
        row += sz; outoff += sz;
    }

    // Write final 64 columns x 16 rows, coalesced on global.
    #pragma unroll
    for (int i = 0; i < 4; ++i) {
        int idx = tid + i * NTHREADS;   // 0..1023
        int c = idx & 63;
        int b = idx >> 6;
        int col = TOTALW - 64 + c;
        const unsigned int* g =
            (const unsigned int*)((const char*)vals + gbyte(col, b >> 3));
        unsigned int d = g[(b & 7) >> 1];
        float v = (b & 1) ? __uint_as_float(d & 0xffff0000u)
                          : __uint_as_float(d << 16);
        out[(size_t)(b0 + b) * 64 + c] = v;
    }
}

extern "C" void kernel_launch(void* const* d_in, const int* in_sizes, int n_in,
                              void* d_out, int out_size, void* d_ws, size_t ws_size,
                              hipStream_t stream) {
    const float* x    = (const float*)d_in[0];
    const float* w    = (const float*)d_in[1];
    const float* bias = (const float*)d_in[2];
    const float* resp = (const float*)d_in[3];
    const int*   src  = (const int*)d_in[4];
    float* out = (float*)d_out;

    const int batch = in_sizes[0] / N_IN;        // 8192
    const int grid  = batch / TILE_B;            // 512 blocks
    neat_eval<<<grid, NTHREADS, 0, stream>>>(x, w, bias, resp, src, out);
}